// Round 11
// baseline (81.629 us; speedup 1.0000x reference)
//
#include <hip/hip_runtime.h>
#include <hip/hip_bf16.h>
#include <hip/hip_fp16.h>

// Problem constants (AttentionModule: B=16, idf=128, cdf=256, H=W=128, L=64)
#define NB  16
#define IDF 128
#define CDF 256
#define LL  64
#define PP  16384      // H*W pixels per batch
#define PXB 256        // px per tile; block = 2 tiles = 512 consecutive px
#define XPA 260        // f32 pitch of the 16x256 attn transpose chunk
#define XPP 516        // f32 pitch of the 16x512 PV transpose chunk

typedef _Float16 f16;
typedef _Float16 f16x4 __attribute__((ext_vector_type(4)));
typedef _Float16 f16x8 __attribute__((ext_vector_type(8)));
typedef float    f32x4 __attribute__((ext_vector_type(4)));

// Lightweight barrier: LDS-order only; global loads/NT stores stay in flight.
#define BAR() do { asm volatile("s_waitcnt lgkmcnt(0)" ::: "memory"); \
                   __builtin_amdgcn_s_barrier(); } while (0)

// ---------------------------------------------------------------------------
// Kernel 1 (merged prep): source = W @ context -> fp16 both orientations;
// block 0 also decodes the mask (int32 or uint8) into 16 x u64 bitmask.
// Mask row used by pixel p is p%16 (torch tile(mask,(P,1)) quirk, proven r2-10).
// ---------------------------------------------------------------------------
__global__ void src_pack_kernel(const float* __restrict__ Wm,
                                const float* __restrict__ ctx,
                                f16* __restrict__ srcF,
                                f16* __restrict__ srcT,
                                const unsigned char* __restrict__ mask_raw,
                                unsigned long long* __restrict__ mbits) {
    if (blockIdx.x == 0) {
        __shared__ int is_u8;
        const int tid = threadIdx.x;
        if (tid == 0) is_u8 = 0;
        if (tid < 16) mbits[tid] = 0ULL;
        __syncthreads();
        unsigned char byt[4];
        #pragma unroll
        for (int q = 0; q < 4; ++q) {
            int k = tid + q * 256;
            byt[q] = mask_raw[k];
            if ((k & 3) != 0 && byt[q] != 0) atomicOr(&is_u8, 1);
        }
        __syncthreads();
        #pragma unroll
        for (int q = 0; q < 4; ++q) {
            int k = tid + q * 256;
            int masked;
            if (is_u8) masked = (byt[q] != 0);
            else       masked = (((const int*)mask_raw)[k] != 0);
            if (masked) atomicOr(&mbits[k >> 6], 1ULL << (unsigned)(k & 63));
        }
    }

    int g = blockIdx.x * 256 + threadIdx.x;      // 0 .. NB*IDF*LL-1
    int l = g & (LL - 1);
    int i = (g >> 6) & (IDF - 1);
    int b = g >> 13;
    const float* wrow = Wm + (size_t)i * CDF;
    const float* ccol = ctx + (size_t)b * CDF * LL + l;
    float s = 0.f;
    #pragma unroll 8
    for (int c = 0; c < CDF; ++c)
        s = fmaf(wrow[c], ccol[(size_t)c * LL], s);
    f16 h = (f16)s;
    srcF[g] = h;                                 // [b][i][l]
    srcT[((size_t)b * LL + l) * IDF + i] = h;    // [b][l][i]
}

// ---------------------------------------------------------------------------
// Kernel 2 (main): block = 4 waves, 512 consecutive px (2 tiles of 256).
// attn_out: per-tile 16x256 chunks (1KB runs) right after each softmax
// (lets acc be reused across tiles). weight/PV: BOTH tiles fused into
// 16x512 chunks -> 2KB contiguous NT-store runs per output row (the r8
// lever, doubled). PV prob fragments for both tiles held in regs (pa0,pa1).
// All MFMA layouts identical to r6-r10 (verified).
// ---------------------------------------------------------------------------
__global__ __launch_bounds__(256, 2)
void attn_mfma_kernel(const float* __restrict__ x,
                      const f16* __restrict__ srcT,
                      const f16* __restrict__ srcF,
                      const unsigned long long* __restrict__ mbits,
                      float* __restrict__ weight,
                      float* __restrict__ attn_out) {
    __shared__ __align__(16) unsigned char s_srcT[LL * 256];    // [l][i] f16, swz
    __shared__ __align__(16) unsigned char s_srcF[IDF * 128];   // [i][l] f16, swz
    __shared__ __align__(16) unsigned char s_u[34816];          // prob / xp bufs

    float* s_xpA = (float*)s_u;                      // attn chunk A [16][XPA]
    float* s_xpB = (float*)(s_u + 16640);            // attn chunk B
    float* s_xpP = (float*)s_u;                      // PV chunk [16][XPP]

    const int b    = blockIdx.y;
    const int tid  = threadIdx.x;
    const int wv   = tid >> 6;         // wave 0..3
    const int lane = tid & 63;
    const int c    = lane & 15;
    const int g    = lane >> 4;
    const int cs   = (c & 7) << 4;     // read-side XOR swizzle (bytes)

    f16* s_pw = (f16*)s_u + (size_t)wv * (64 * 68);  // per-wave prob [64px][68]

    // XCD swizzle: grid.x = 32 = 8 XCDs x 4 consecutive 512-px blocks
    const int bxs = (blockIdx.x & 7) * 4 + (blockIdx.x >> 3);
    const int pwb = bxs * (2 * PXB);                 // block pixel base (512)
    const float* xb0 = x + (size_t)b * IDF * PP + pwb + wv * 64 + c; // tile0
    const float* xb1 = xb0 + PXB;                                    // tile1

    // ---- mask bits for this lane's pixel rows (p%16 = 4g+r)
    unsigned mlo[4], mhi[4];
    #pragma unroll
    for (int r = 0; r < 4; ++r) {
        unsigned long long m = mbits[4 * g + r];
        mlo[r] = (unsigned)m;
        mhi[r] = (unsigned)(m >> 32);
    }

    float xfa[32], xfb[32];
    f32x4 acc[4][4];          // reused per tile
    f16x8 pa0[4][2], pa1[4][2];

#define QK_LOAD(BUF, KS, XB)                                                \
    {   _Pragma("unroll")                                                   \
        for (int pt = 0; pt < 4; ++pt)                                      \
            _Pragma("unroll")                                               \
            for (int j = 0; j < 8; ++j)                                     \
                BUF[pt * 8 + j] =                                           \
                    (XB)[(size_t)((KS) * 32 + 8 * g + j) * PP + pt * 16];   \
    }

#define QK_STEP(BUF, KS)                                                    \
    {   f16x8 xa_[4];                                                       \
        _Pragma("unroll")                                                   \
        for (int pt = 0; pt < 4; ++pt)                                      \
            _Pragma("unroll")                                               \
            for (int j = 0; j < 8; ++j) xa_[pt][j] = (f16)BUF[pt * 8 + j];  \
        _Pragma("unroll")                                                   \
        for (int nt = 0; nt < 4; ++nt) {                                    \
            const f16x8 bt = *reinterpret_cast<const f16x8*>(               \
                s_srcT + (nt * 16 + c) * 256 + (((KS) * 64 + 16 * g) ^ cs));\
            _Pragma("unroll")                                               \
            for (int pt = 0; pt < 4; ++pt)                                  \
                acc[pt][nt] = __builtin_amdgcn_mfma_f32_16x16x32_f16(       \
                    xa_[pt], bt, acc[pt][nt], 0, 0, 0);                     \
        } }

#define ACC_ZERO()                                                          \
    {   _Pragma("unroll")                                                   \
        for (int pt = 0; pt < 4; ++pt)                                      \
            _Pragma("unroll")                                               \
            for (int nt = 0; nt < 4; ++nt)                                  \
                acc[pt][nt] = (f32x4){0.f, 0.f, 0.f, 0.f}; }

#define SOFTMAX()                                                           \
    {   _Pragma("unroll")                                                   \
        for (int r = 0; r < 4; ++r) {                                       \
            const unsigned m0 = (mlo[r] >> c) & 1u;                         \
            const unsigned m1 = (mlo[r] >> (16 + c)) & 1u;                  \
            const unsigned m2 = (mhi[r] >> c) & 1u;                         \
            const unsigned m3 = (mhi[r] >> (16 + c)) & 1u;                  \
            _Pragma("unroll")                                               \
            for (int pt = 0; pt < 4; ++pt) {                                \
                if (m0) acc[pt][0][r] = -INFINITY;                          \
                if (m1) acc[pt][1][r] = -INFINITY;                          \
                if (m2) acc[pt][2][r] = -INFINITY;                          \
                if (m3) acc[pt][3][r] = -INFINITY;                          \
            }                                                               \
        }                                                                   \
        _Pragma("unroll")                                                   \
        for (int pt = 0; pt < 4; ++pt) {                                    \
            _Pragma("unroll")                                               \
            for (int r = 0; r < 4; ++r) {                                   \
                float mx = fmaxf(fmaxf(acc[pt][0][r], acc[pt][1][r]),       \
                                 fmaxf(acc[pt][2][r], acc[pt][3][r]));      \
                mx = fmaxf(mx, __shfl_xor(mx, 1, 64));                      \
                mx = fmaxf(mx, __shfl_xor(mx, 2, 64));                      \
                mx = fmaxf(mx, __shfl_xor(mx, 4, 64));                      \
                mx = fmaxf(mx, __shfl_xor(mx, 8, 64));                      \
                float sum = 0.f;                                            \
                _Pragma("unroll")                                           \
                for (int nt = 0; nt < 4; ++nt) {                            \
                    float e = exp2f((acc[pt][nt][r] - mx) * 1.44269504f);   \
                    acc[pt][nt][r] = e;                                     \
                    sum += e;                                               \
                }                                                           \
                sum += __shfl_xor(sum, 1, 64);                              \
                sum += __shfl_xor(sum, 2, 64);                              \
                sum += __shfl_xor(sum, 4, 64);                              \
                sum += __shfl_xor(sum, 8, 64);                              \
                const float inv = 1.f / sum;                                \
                _Pragma("unroll")                                           \
                for (int nt = 0; nt < 4; ++nt) acc[pt][nt][r] *= inv;       \
            }                                                               \
        } }

    // prob -> per-wave LDS tile (pitch 68 f16), read PV A-frags back into PA
    // (same-wave RAW ordering, proven r4-r10).
#define PROB_EXCHANGE(PA)                                                   \
    {   _Pragma("unroll")                                                   \
        for (int pt = 0; pt < 4; ++pt)                                      \
            _Pragma("unroll")                                               \
            for (int nt = 0; nt < 4; ++nt)                                  \
                _Pragma("unroll")                                           \
                for (int r = 0; r < 4; ++r)                                 \
                    s_pw[(pt * 16 + 4 * g + r) * 68 + nt * 16 + c] =        \
                        (f16)acc[pt][nt][r];                                \
        _Pragma("unroll")                                                   \
        for (int pt = 0; pt < 4; ++pt)                                      \
            _Pragma("unroll")                                               \
            for (int ks = 0; ks < 2; ++ks) {                                \
                const f16* pp = s_pw + (pt * 16 + c) * 68 + ks * 32 + 8 * g;\
                f16x4 lo = *reinterpret_cast<const f16x4*>(pp);             \
                f16x4 hi = *reinterpret_cast<const f16x4*>(pp + 4);         \
                f16x8 v;                                                    \
                _Pragma("unroll")                                           \
                for (int j = 0; j < 4; ++j) { v[j] = lo[j]; v[4+j] = hi[j]; } \
                PA[pt][ks] = v;                                             \
            } }

    // ---- attn chunk: 16 l-rows x 256 px (per tile), double-buffered
#define FILL_ATTN(NT, XP)                                                   \
    {   _Pragma("unroll")                                                   \
        for (int pt = 0; pt < 4; ++pt)                                      \
            *reinterpret_cast<f32x4*>(                                      \
                (XP) + c * XPA + wv * 64 + pt * 16 + 4 * g) = acc[pt][NT]; }

#define STORE_A(K, XP, AB)                                                  \
    {   _Pragma("unroll")                                                   \
        for (int k2 = 0; k2 < 4; ++k2) {                                    \
            int f = tid + k2 * 256;                                         \
            int row = f >> 6, u = f & 63;                                   \
            f32x4 v = *reinterpret_cast<const f32x4*>(                      \
                (XP) + row * XPA + u * 4);                                  \
            __builtin_nontemporal_store(v,                                  \
                reinterpret_cast<f32x4*>((AB) + (size_t)((K) * 16 + row) * PP + u * 4)); \
        } }

    // ---- PV chunk: 16 i-rows x 512 px (BOTH tiles) -> 2KB runs
#define FILL_PV(CH)                                                         \
    {   f32x4 a2[8];                                                        \
        _Pragma("unroll")                                                   \
        for (int q = 0; q < 8; ++q) a2[q] = (f32x4){0.f, 0.f, 0.f, 0.f};    \
        _Pragma("unroll")                                                   \
        for (int ks = 0; ks < 2; ++ks) {                                    \
            const f16x8 sf = *reinterpret_cast<const f16x8*>(               \
                s_srcF + ((CH) * 16 + c) * 128 + ((ks * 64 + 16 * g) ^ cs));\
            _Pragma("unroll")                                               \
            for (int pt = 0; pt < 4; ++pt) {                                \
                a2[pt]     = __builtin_amdgcn_mfma_f32_16x16x32_f16(        \
                    pa0[pt][ks], sf, a2[pt], 0, 0, 0);                      \
                a2[4 + pt] = __builtin_amdgcn_mfma_f32_16x16x32_f16(        \
                    pa1[pt][ks], sf, a2[4 + pt], 0, 0, 0);                  \
            }                                                               \
        }                                                                   \
        _Pragma("unroll")                                                   \
        for (int tl = 0; tl < 2; ++tl)                                      \
            _Pragma("unroll")                                               \
            for (int pt = 0; pt < 4; ++pt)                                  \
                *reinterpret_cast<f32x4*>(                                  \
                    s_xpP + c * XPP + tl * 256 + wv * 64 + pt * 16 + 4 * g) \
                    = a2[tl * 4 + pt]; }

#define STORE_PV(CH, WB)                                                    \
    {   _Pragma("unroll")                                                   \
        for (int k2 = 0; k2 < 8; ++k2) {                                    \
            int f = tid + k2 * 256;                                         \
            int row = f >> 7, u = f & 127;                                  \
            f32x4 v = *reinterpret_cast<const f32x4*>(                      \
                s_xpP + row * XPP + u * 4);                                 \
            __builtin_nontemporal_store(v,                                  \
                reinterpret_cast<f32x4*>((WB) + (size_t)((CH) * 16 + row) * PP + u * 4)); \
        } }

    // =========================== prologue ================================
    QK_LOAD(xfa, 0, xb0)     // first tile-0 loads before staging

    {   // stage srcT (16KB) + srcF (16KB) into LDS, write-side swizzled
        const f16* sT = srcT + (size_t)b * LL * IDF;
        const f16* sF = srcF + (size_t)b * IDF * LL;
        #pragma unroll
        for (int it = 0; it < 4; ++it) {
            int e = (it * 256 + tid) * 8;
            int l = e >> 7, i = e & 127;
            f16x8 v = *reinterpret_cast<const f16x8*>(sT + l * IDF + i);
            *reinterpret_cast<f16x8*>(
                s_srcT + l * 256 + ((i * 2) ^ ((l & 7) << 4))) = v;
        }
        #pragma unroll
        for (int it = 0; it < 4; ++it) {
            int e = (it * 256 + tid) * 8;
            int i = e >> 6, l = e & 63;
            f16x8 v = *reinterpret_cast<const f16x8*>(sF + i * LL + l);
            *reinterpret_cast<f16x8*>(
                s_srcF + i * 128 + ((l * 2) ^ ((i & 7) << 4))) = v;
        }
    }
    BAR();   // B0: staging done

    float* abase0 = attn_out + (size_t)b * LL * PP + pwb;
    float* abase1 = abase0 + PXB;
    float* wbase  = weight + (size_t)b * IDF * PP + pwb;

    // =========================== tile 0 =================================
    ACC_ZERO()
    QK_LOAD(xfb, 1, xb0)
    QK_STEP(xfa, 0)
    QK_LOAD(xfa, 2, xb0)
    QK_STEP(xfb, 1)
    QK_LOAD(xfb, 3, xb0)
    QK_STEP(xfa, 2)
    QK_STEP(xfb, 3)
    SOFTMAX()
    PROB_EXCHANGE(pa0)
    BAR();   // prob readbacks done; s_u becomes attn xp buffers

    // attn chunks tile0 (double-buffered); tile-1 x loads issued underneath
    FILL_ATTN(0, s_xpA)
    BAR();
    STORE_A(0, s_xpA, abase0) QK_LOAD(xfa, 0, xb1) FILL_ATTN(1, s_xpB) BAR();
    STORE_A(1, s_xpB, abase0) QK_LOAD(xfb, 1, xb1) FILL_ATTN(2, s_xpA) BAR();
    STORE_A(2, s_xpA, abase0) FILL_ATTN(3, s_xpB) BAR();
    STORE_A(3, s_xpB, abase0)
    BAR();   // all attn-t0 xp reads done

    // =========================== tile 1 =================================
    ACC_ZERO()
    QK_STEP(xfa, 0)
    QK_LOAD(xfa, 2, xb1)
    QK_STEP(xfb, 1)
    QK_LOAD(xfb, 3, xb1)
    QK_STEP(xfa, 2)
    QK_STEP(xfb, 3)
    SOFTMAX()
    PROB_EXCHANGE(pa1)
    BAR();   // prob readbacks done

    FILL_ATTN(0, s_xpA)
    BAR();
    STORE_A(0, s_xpA, abase1) FILL_ATTN(1, s_xpB) BAR();
    STORE_A(1, s_xpB, abase1) FILL_ATTN(2, s_xpA) BAR();
    STORE_A(2, s_xpA, abase1) FILL_ATTN(3, s_xpB) BAR();
    STORE_A(3, s_xpB, abase1)
    BAR();   // all attn-t1 xp reads done; s_u becomes PV buffer

    // ==================== PV: 8 chunks of 16 x 512 ======================
    FILL_PV(0) BAR(); STORE_PV(0, wbase) BAR();
    FILL_PV(1) BAR(); STORE_PV(1, wbase) BAR();
    FILL_PV(2) BAR(); STORE_PV(2, wbase) BAR();
    FILL_PV(3) BAR(); STORE_PV(3, wbase) BAR();
    FILL_PV(4) BAR(); STORE_PV(4, wbase) BAR();
    FILL_PV(5) BAR(); STORE_PV(5, wbase) BAR();
    FILL_PV(6) BAR(); STORE_PV(6, wbase) BAR();
    FILL_PV(7) BAR(); STORE_PV(7, wbase)
    // kernel end: implicit full waitcnt drains stores
}

// ---------------------------------------------------------------------------
extern "C" void kernel_launch(void* const* d_in, const int* in_sizes, int n_in,
                              void* d_out, int out_size, void* d_ws, size_t ws_size,
                              hipStream_t stream) {
    const float*         x        = (const float*)d_in[0];
    const float*         ctx      = (const float*)d_in[1];
    const float*         Wm       = (const float*)d_in[2];
    const unsigned char* mask_raw = (const unsigned char*)d_in[3];

    float* weight   = (float*)d_out;                     // [B, IDF, H, W]
    float* attn_out = weight + (size_t)NB * IDF * PP;    // [B, L, H, W]

    // workspace: mbits u64[16] | srcF fp16 (256KB) | srcT fp16 (256KB)
    unsigned long long* mbits = (unsigned long long*)d_ws;
    f16* srcF = (f16*)((char*)d_ws + 4096);
    f16* srcT = srcF + (size_t)NB * IDF * LL;

    src_pack_kernel<<<(NB * IDF * LL) / 256, 256, 0, stream>>>(
        Wm, ctx, srcF, srcT, mask_raw, mbits);

    dim3 grid(PP / (2 * PXB), NB);
    attn_mfma_kernel<<<grid, 256, 0, stream>>>(x, srcT, srcF, mbits, weight, attn_out);
}

// Round 12
// 72.751 us; speedup vs baseline: 1.1220x; 1.1220x over previous
//
#include <hip/hip_runtime.h>
#include <hip/hip_bf16.h>
#include <hip/hip_fp16.h>

// Problem constants (AttentionModule: B=16, idf=128, cdf=256, H=W=128, L=64)
#define NB  16
#define IDF 128
#define CDF 256
#define LL  64
#define PP  16384      // H*W pixels per batch
#define PXB 256        // pixels per block (consecutive) -> 1KB store runs
#define XPITCH 260     // f32 pitch of the 16x256 transpose chunk

typedef _Float16 f16;
typedef _Float16 f16x4 __attribute__((ext_vector_type(4)));
typedef _Float16 f16x8 __attribute__((ext_vector_type(8)));
typedef float    f32x4 __attribute__((ext_vector_type(4)));

// Lightweight barrier: LDS-order only; global loads/NT stores stay in flight.
#define BAR() do { asm volatile("s_waitcnt lgkmcnt(0)" ::: "memory"); \
                   __builtin_amdgcn_s_barrier(); } while (0)

// ---------------------------------------------------------------------------
// Kernel 1 (merged prep): source = W @ context -> fp16 both orientations;
// block 0 also decodes the mask (int32 or uint8) into 16 x u64 bitmask.
// Mask row used by pixel p is p%16 (torch tile(mask,(P,1)) quirk, proven r2-11).
// ---------------------------------------------------------------------------
__global__ void src_pack_kernel(const float* __restrict__ Wm,
                                const float* __restrict__ ctx,
                                f16* __restrict__ srcF,
                                f16* __restrict__ srcT,
                                const unsigned char* __restrict__ mask_raw,
                                unsigned long long* __restrict__ mbits) {
    if (blockIdx.x == 0) {
        __shared__ int is_u8;
        const int tid = threadIdx.x;
        if (tid == 0) is_u8 = 0;
        if (tid < 16) mbits[tid] = 0ULL;
        __syncthreads();
        unsigned char byt[4];
        #pragma unroll
        for (int q = 0; q < 4; ++q) {
            int k = tid + q * 256;
            byt[q] = mask_raw[k];
            if ((k & 3) != 0 && byt[q] != 0) atomicOr(&is_u8, 1);
        }
        __syncthreads();
        #pragma unroll
        for (int q = 0; q < 4; ++q) {
            int k = tid + q * 256;
            int masked;
            if (is_u8) masked = (byt[q] != 0);
            else       masked = (((const int*)mask_raw)[k] != 0);
            if (masked) atomicOr(&mbits[k >> 6], 1ULL << (unsigned)(k & 63));
        }
    }

    int g = blockIdx.x * 256 + threadIdx.x;      // 0 .. NB*IDF*LL-1
    int l = g & (LL - 1);
    int i = (g >> 6) & (IDF - 1);
    int b = g >> 13;
    const float* wrow = Wm + (size_t)i * CDF;
    const float* ccol = ctx + (size_t)b * CDF * LL + l;
    float s = 0.f;
    #pragma unroll 8
    for (int c = 0; c < CDF; ++c)
        s = fmaf(wrow[c], ccol[(size_t)c * LL], s);
    f16 h = (f16)s;
    srcF[g] = h;                                 // [b][i][l]
    srcT[((size_t)b * LL + l) * IDF + i] = h;    // [b][l][i]
}

// ---------------------------------------------------------------------------
// Kernel 2 (main): r9 structure (block = 4 waves = 256 consecutive px,
// 12 transpose chunks of 16x256 -> 1KB NT-store runs), with LDS cut to
// ~49KB for 3 blocks/CU: halved per-wave prob tile ([32][68], two-half
// exchange via same-wave DS ordering) + single-buffered xp chunk.
// Cross-block TLP replaces intra-block FILL/STORE overlap.
// All MFMA layouts identical to r6-r11 (verified).
// ---------------------------------------------------------------------------
__global__ __launch_bounds__(256, 3)
void attn_mfma_kernel(const float* __restrict__ x,
                      const f16* __restrict__ srcT,
                      const f16* __restrict__ srcF,
                      const unsigned long long* __restrict__ mbits,
                      float* __restrict__ weight,
                      float* __restrict__ attn_out) {
    __shared__ __align__(16) unsigned char s_srcT[LL * 256];    // [l][i] f16, swz
    __shared__ __align__(16) unsigned char s_srcF[IDF * 128];   // [i][l] f16, swz
    __shared__ __align__(16) unsigned char s_u[17408];          // prob halves / xp

    float* s_xp = (float*)s_u;                       // [16][XPITCH] f32 chunk

    const int b    = blockIdx.y;
    const int tid  = threadIdx.x;
    const int wv   = tid >> 6;         // wave 0..3
    const int lane = tid & 63;
    const int c    = lane & 15;
    const int g    = lane >> 4;
    const int cs   = (c & 7) << 4;     // read-side XOR swizzle (bytes)

    f16* s_pw = (f16*)(s_u + (size_t)wv * 4352);     // per-wave prob [32px][68]

    // XCD swizzle: grid.x = 64 = 8 XCDs x 8 consecutive pixel-blocks
    const int bxs = (blockIdx.x & 7) * 8 + (blockIdx.x >> 3);
    const int pwb = bxs * PXB;                       // block pixel base
    const int pww = pwb + wv * 64;                   // wave pixel base (64 px)
    const float* xb = x + (size_t)b * IDF * PP + pww + c;

    // ---- mask bits for this lane's pixel rows (p%16 = 4g+r)
    unsigned mlo[4], mhi[4];
    #pragma unroll
    for (int r = 0; r < 4; ++r) {
        unsigned long long m = mbits[4 * g + r];
        mlo[r] = (unsigned)m;
        mhi[r] = (unsigned)(m >> 32);
    }

    float xfa[32], xfb[32];
    f32x4 acc[4][4];
    f16x8 pa[4][2];

#define QK_LOAD(BUF, KS)                                                    \
    {   _Pragma("unroll")                                                   \
        for (int pt = 0; pt < 4; ++pt)                                      \
            _Pragma("unroll")                                               \
            for (int j = 0; j < 8; ++j)                                     \
                BUF[pt * 8 + j] =                                           \
                    xb[(size_t)((KS) * 32 + 8 * g + j) * PP + pt * 16];     \
    }

#define QK_STEP(BUF, KS)                                                    \
    {   f16x8 xa_[4];                                                       \
        _Pragma("unroll")                                                   \
        for (int pt = 0; pt < 4; ++pt)                                      \
            _Pragma("unroll")                                               \
            for (int j = 0; j < 8; ++j) xa_[pt][j] = (f16)BUF[pt * 8 + j];  \
        _Pragma("unroll")                                                   \
        for (int nt = 0; nt < 4; ++nt) {                                    \
            const f16x8 bt = *reinterpret_cast<const f16x8*>(               \
                s_srcT + (nt * 16 + c) * 256 + (((KS) * 64 + 16 * g) ^ cs));\
            _Pragma("unroll")                                               \
            for (int pt = 0; pt < 4; ++pt)                                  \
                acc[pt][nt] = __builtin_amdgcn_mfma_f32_16x16x32_f16(       \
                    xa_[pt], bt, acc[pt][nt], 0, 0, 0);                     \
        } }

    // =========================== prologue ================================
    QK_LOAD(xfa, 0)          // first x loads before staging

    {   // stage srcT (16KB) + srcF (16KB) into LDS, write-side swizzled
        const f16* sT = srcT + (size_t)b * LL * IDF;
        const f16* sF = srcF + (size_t)b * IDF * LL;
        #pragma unroll
        for (int it = 0; it < 4; ++it) {
            int e = (it * 256 + tid) * 8;
            int l = e >> 7, i = e & 127;
            f16x8 v = *reinterpret_cast<const f16x8*>(sT + l * IDF + i);
            *reinterpret_cast<f16x8*>(
                s_srcT + l * 256 + ((i * 2) ^ ((l & 7) << 4))) = v;
        }
        #pragma unroll
        for (int it = 0; it < 4; ++it) {
            int e = (it * 256 + tid) * 8;
            int i = e >> 6, l = e & 63;
            f16x8 v = *reinterpret_cast<const f16x8*>(sF + i * LL + l);
            *reinterpret_cast<f16x8*>(
                s_srcF + i * 128 + ((l * 2) ^ ((i & 7) << 4))) = v;
        }
    }
    BAR();   // B0: staging done

    // ============================= QK^T ==================================
    #pragma unroll
    for (int pt = 0; pt < 4; ++pt)
        #pragma unroll
        for (int nt = 0; nt < 4; ++nt) acc[pt][nt] = (f32x4){0.f, 0.f, 0.f, 0.f};

    QK_LOAD(xfb, 1)
    QK_STEP(xfa, 0)
    QK_LOAD(xfa, 2)
    QK_STEP(xfb, 1)
    QK_LOAD(xfb, 3)
    QK_STEP(xfa, 2)
    QK_STEP(xfb, 3)

    // ======================= masked softmax over l =======================
    #pragma unroll
    for (int r = 0; r < 4; ++r) {
        const unsigned m0 = (mlo[r] >> c) & 1u;
        const unsigned m1 = (mlo[r] >> (16 + c)) & 1u;
        const unsigned m2 = (mhi[r] >> c) & 1u;
        const unsigned m3 = (mhi[r] >> (16 + c)) & 1u;
        #pragma unroll
        for (int pt = 0; pt < 4; ++pt) {
            if (m0) acc[pt][0][r] = -INFINITY;
            if (m1) acc[pt][1][r] = -INFINITY;
            if (m2) acc[pt][2][r] = -INFINITY;
            if (m3) acc[pt][3][r] = -INFINITY;
        }
    }
    #pragma unroll
    for (int pt = 0; pt < 4; ++pt) {
        #pragma unroll
        for (int r = 0; r < 4; ++r) {
            float mx = fmaxf(fmaxf(acc[pt][0][r], acc[pt][1][r]),
                             fmaxf(acc[pt][2][r], acc[pt][3][r]));
            mx = fmaxf(mx, __shfl_xor(mx, 1, 64));
            mx = fmaxf(mx, __shfl_xor(mx, 2, 64));
            mx = fmaxf(mx, __shfl_xor(mx, 4, 64));
            mx = fmaxf(mx, __shfl_xor(mx, 8, 64));
            float sum = 0.f;
            #pragma unroll
            for (int nt = 0; nt < 4; ++nt) {
                float e = exp2f((acc[pt][nt][r] - mx) * 1.44269504f);
                acc[pt][nt][r] = e;
                sum += e;
            }
            sum += __shfl_xor(sum, 1, 64);
            sum += __shfl_xor(sum, 2, 64);
            sum += __shfl_xor(sum, 4, 64);
            sum += __shfl_xor(sum, 8, 64);
            const float inv = 1.f / sum;
            #pragma unroll
            for (int nt = 0; nt < 4; ++nt) acc[pt][nt][r] *= inv;
        }
    }

    // ---- prob -> PV A-frags via HALVED per-wave LDS tile [32px][68].
    //      Two pt-halves; same-wave DS ordering (RAW + WAR) covers reuse
    //      (mechanism proven r4-r11). No barrier needed.
    #pragma unroll
    for (int h = 0; h < 2; ++h) {
        #pragma unroll
        for (int pl = 0; pl < 2; ++pl) {           // pt = h*2 + pl
            const int pt = h * 2 + pl;
            #pragma unroll
            for (int nt = 0; nt < 4; ++nt)
                #pragma unroll
                for (int r = 0; r < 4; ++r)
                    s_pw[(pl * 16 + 4 * g + r) * 68 + nt * 16 + c] =
                        (f16)acc[pt][nt][r];
        }
        #pragma unroll
        for (int pl = 0; pl < 2; ++pl) {
            const int pt = h * 2 + pl;
            #pragma unroll
            for (int ks = 0; ks < 2; ++ks) {
                const f16* pp = s_pw + (pl * 16 + c) * 68 + ks * 32 + 8 * g;
                f16x4 lo = *reinterpret_cast<const f16x4*>(pp);
                f16x4 hi = *reinterpret_cast<const f16x4*>(pp + 4);
                f16x8 v;
                #pragma unroll
                for (int j = 0; j < 4; ++j) { v[j] = lo[j]; v[4 + j] = hi[j]; }
                pa[pt][ks] = v;
            }
        }
    }
    BAR();   // prob exchange done; s_u becomes the xp chunk buffer

    float* abase = attn_out + (size_t)b * LL * PP + pwb;
    float* wbase = weight + (size_t)b * IDF * PP + pwb;

#define FILL_ATTN(NT)                                                       \
    {   _Pragma("unroll")                                                   \
        for (int pt = 0; pt < 4; ++pt)                                      \
            *reinterpret_cast<f32x4*>(                                      \
                s_xp + c * XPITCH + wv * 64 + pt * 16 + 4 * g) = acc[pt][NT]; }

#define FILL_PV(CH)                                                         \
    {   f32x4 a2[4];                                                        \
        _Pragma("unroll")                                                   \
        for (int pt = 0; pt < 4; ++pt) a2[pt] = (f32x4){0.f, 0.f, 0.f, 0.f};\
        _Pragma("unroll")                                                   \
        for (int ks = 0; ks < 2; ++ks) {                                    \
            const f16x8 sf = *reinterpret_cast<const f16x8*>(               \
                s_srcF + ((CH) * 16 + c) * 128 + ((ks * 64 + 16 * g) ^ cs));\
            _Pragma("unroll")                                               \
            for (int pt = 0; pt < 4; ++pt)                                  \
                a2[pt] = __builtin_amdgcn_mfma_f32_16x16x32_f16(            \
                    pa[pt][ks], sf, a2[pt], 0, 0, 0);                       \
        }                                                                   \
        _Pragma("unroll")                                                   \
        for (int pt = 0; pt < 4; ++pt)                                      \
            *reinterpret_cast<f32x4*>(                                      \
                s_xp + c * XPITCH + wv * 64 + pt * 16 + 4 * g) = a2[pt]; }

#define STORE_CHUNK(K)                                                      \
    {   float* dst = ((K) < 4)                                              \
            ? (abase + (size_t)((K) * 16) * PP)                             \
            : (wbase + (size_t)(((K) - 4) * 16) * PP);                      \
        _Pragma("unroll")                                                   \
        for (int k2 = 0; k2 < 4; ++k2) {                                    \
            int f = tid + k2 * 256;                                         \
            int row = f >> 6, u = f & 63;                                   \
            f32x4 v = *reinterpret_cast<const f32x4*>(                      \
                s_xp + row * XPITCH + u * 4);                               \
            __builtin_nontemporal_store(v,                                  \
                reinterpret_cast<f32x4*>(dst + (size_t)row * PP + u * 4));  \
        } }

#define CHUNK(K)                                                            \
    {   if ((K) < 4) { FILL_ATTN(K) } else { FILL_PV((K) - 4) }             \
        BAR();                                                              \
        STORE_CHUNK(K)                                                      \
        BAR(); }

    // ---- 12 chunks (4 attn + 8 PV), single-buffered; cross-block TLP
    //      (3 blocks/CU) hides the FILL/STORE serialization.
    CHUNK(0)  CHUNK(1)  CHUNK(2)  CHUNK(3)
    CHUNK(4)  CHUNK(5)  CHUNK(6)  CHUNK(7)
    CHUNK(8)  CHUNK(9)  CHUNK(10)
    { FILL_PV(7) BAR(); STORE_CHUNK(11) }   // last: no trailing barrier
    // kernel end: implicit full waitcnt drains stores
}

// ---------------------------------------------------------------------------
extern "C" void kernel_launch(void* const* d_in, const int* in_sizes, int n_in,
                              void* d_out, int out_size, void* d_ws, size_t ws_size,
                              hipStream_t stream) {
    const float*         x        = (const float*)d_in[0];
    const float*         ctx      = (const float*)d_in[1];
    const float*         Wm       = (const float*)d_in[2];
    const unsigned char* mask_raw = (const unsigned char*)d_in[3];

    float* weight   = (float*)d_out;                     // [B, IDF, H, W]
    float* attn_out = weight + (size_t)NB * IDF * PP;    // [B, L, H, W]

    // workspace: mbits u64[16] | srcF fp16 (256KB) | srcT fp16 (256KB)
    unsigned long long* mbits = (unsigned long long*)d_ws;
    f16* srcF = (f16*)((char*)d_ws + 4096);
    f16* srcT = srcF + (size_t)NB * IDF * LL;

    src_pack_kernel<<<(NB * IDF * LL) / 256, 256, 0, stream>>>(
        Wm, ctx, srcF, srcT, mask_raw, mbits);

    dim3 grid(PP / PXB, NB);
    attn_mfma_kernel<<<grid, 256, 0, stream>>>(x, srcT, srcF, mbits, weight, attn_out);
}

// Round 13
// 72.660 us; speedup vs baseline: 1.1234x; 1.0013x over previous
//
#include <hip/hip_runtime.h>
#include <hip/hip_bf16.h>
#include <hip/hip_fp16.h>

// Problem constants (AttentionModule: B=16, idf=128, cdf=256, H=W=128, L=64)
#define NB  16
#define IDF 128
#define CDF 256
#define LL  64
#define PP  16384      // H*W pixels per batch
#define PXB 256        // pixels per block (consecutive) -> 1KB store runs
#define XPITCH 260     // f32 pitch of the 16x256 transpose chunk

typedef _Float16 f16;
typedef _Float16 f16x4 __attribute__((ext_vector_type(4)));
typedef _Float16 f16x8 __attribute__((ext_vector_type(8)));
typedef float    f32x4 __attribute__((ext_vector_type(4)));

// Lightweight barrier: LDS-order only; global loads/NT stores stay in flight.
#define BAR() do { asm volatile("s_waitcnt lgkmcnt(0)" ::: "memory"); \
                   __builtin_amdgcn_s_barrier(); } while (0)

// ---------------------------------------------------------------------------
// Kernel 1 (merged prep): source = W @ context -> fp16 both orientations;
// block 0 also decodes the mask (int32 or uint8) into 16 x u64 bitmask.
// Mask row used by pixel p is p%16 (torch tile(mask,(P,1)) quirk, proven r2-12).
// ---------------------------------------------------------------------------
__global__ void src_pack_kernel(const float* __restrict__ Wm,
                                const float* __restrict__ ctx,
                                f16* __restrict__ srcF,
                                f16* __restrict__ srcT,
                                const unsigned char* __restrict__ mask_raw,
                                unsigned long long* __restrict__ mbits) {
    if (blockIdx.x == 0) {
        __shared__ int is_u8;
        const int tid = threadIdx.x;
        if (tid == 0) is_u8 = 0;
        if (tid < 16) mbits[tid] = 0ULL;
        __syncthreads();
        unsigned char byt[4];
        #pragma unroll
        for (int q = 0; q < 4; ++q) {
            int k = tid + q * 256;
            byt[q] = mask_raw[k];
            if ((k & 3) != 0 && byt[q] != 0) atomicOr(&is_u8, 1);
        }
        __syncthreads();
        #pragma unroll
        for (int q = 0; q < 4; ++q) {
            int k = tid + q * 256;
            int masked;
            if (is_u8) masked = (byt[q] != 0);
            else       masked = (((const int*)mask_raw)[k] != 0);
            if (masked) atomicOr(&mbits[k >> 6], 1ULL << (unsigned)(k & 63));
        }
    }

    int g = blockIdx.x * 256 + threadIdx.x;      // 0 .. NB*IDF*LL-1
    int l = g & (LL - 1);
    int i = (g >> 6) & (IDF - 1);
    int b = g >> 13;
    const float* wrow = Wm + (size_t)i * CDF;
    const float* ccol = ctx + (size_t)b * CDF * LL + l;
    float s = 0.f;
    #pragma unroll 8
    for (int c = 0; c < CDF; ++c)
        s = fmaf(wrow[c], ccol[(size_t)c * LL], s);
    f16 h = (f16)s;
    srcF[g] = h;                                 // [b][i][l]
    srcT[((size_t)b * LL + l) * IDF + i] = h;    // [b][l][i]
}

// ---------------------------------------------------------------------------
// Kernel 2 (main): 512-thread block = 8 waves x 32 px = 256 consecutive px.
// Same chunk pipeline as r12 (12 x 16-row x 256-px chunks, 1KB NT runs,
// single-buffered, lgkm-only barriers) but per-wave state halved
// (acc[2][4], ~115 VGPR) -> 16 waves/CU (vs 12) at 2 blocks/CU.
// All MFMA layouts identical to r6-r12 (verified).
// ---------------------------------------------------------------------------
__global__ __launch_bounds__(512, 4)
void attn_mfma_kernel(const float* __restrict__ x,
                      const f16* __restrict__ srcT,
                      const f16* __restrict__ srcF,
                      const unsigned long long* __restrict__ mbits,
                      float* __restrict__ weight,
                      float* __restrict__ attn_out) {
    __shared__ __align__(16) unsigned char s_srcT[LL * 256];    // [l][i] f16, swz
    __shared__ __align__(16) unsigned char s_srcF[IDF * 128];   // [i][l] f16, swz
    __shared__ __align__(16) unsigned char s_u[34816];          // prob tiles / xp

    float* s_xp = (float*)s_u;                       // [16][XPITCH] f32 chunk

    const int b    = blockIdx.y;
    const int tid  = threadIdx.x;
    const int wv   = tid >> 6;         // wave 0..7
    const int lane = tid & 63;
    const int c    = lane & 15;
    const int g    = lane >> 4;
    const int cs   = (c & 7) << 4;     // read-side XOR swizzle (bytes)

    f16* s_pw = (f16*)(s_u + (size_t)wv * 4352);     // per-wave prob [32px][68]

    // XCD swizzle: grid.x = 64 = 8 XCDs x 8 consecutive pixel-blocks
    const int bxs = (blockIdx.x & 7) * 8 + (blockIdx.x >> 3);
    const int pwb = bxs * PXB;                       // block pixel base
    const int pww = pwb + wv * 32;                   // wave pixel base (32 px)
    const float* xb = x + (size_t)b * IDF * PP + pww + c;

    // ---- mask bits for this lane's pixel rows (p%16 = 4g+r)
    unsigned mlo[4], mhi[4];
    #pragma unroll
    for (int r = 0; r < 4; ++r) {
        unsigned long long m = mbits[4 * g + r];
        mlo[r] = (unsigned)m;
        mhi[r] = (unsigned)(m >> 32);
    }

    float xfa[16], xfb[16];
    f32x4 acc[2][4];
    f16x8 pa[2][2];

#define QK_LOAD(BUF, KS)                                                    \
    {   _Pragma("unroll")                                                   \
        for (int pt = 0; pt < 2; ++pt)                                      \
            _Pragma("unroll")                                               \
            for (int j = 0; j < 8; ++j)                                     \
                BUF[pt * 8 + j] =                                           \
                    xb[(size_t)((KS) * 32 + 8 * g + j) * PP + pt * 16];     \
    }

#define QK_STEP(BUF, KS)                                                    \
    {   f16x8 xa_[2];                                                       \
        _Pragma("unroll")                                                   \
        for (int pt = 0; pt < 2; ++pt)                                      \
            _Pragma("unroll")                                               \
            for (int j = 0; j < 8; ++j) xa_[pt][j] = (f16)BUF[pt * 8 + j];  \
        _Pragma("unroll")                                                   \
        for (int nt = 0; nt < 4; ++nt) {                                    \
            const f16x8 bt = *reinterpret_cast<const f16x8*>(               \
                s_srcT + (nt * 16 + c) * 256 + (((KS) * 64 + 16 * g) ^ cs));\
            _Pragma("unroll")                                               \
            for (int pt = 0; pt < 2; ++pt)                                  \
                acc[pt][nt] = __builtin_amdgcn_mfma_f32_16x16x32_f16(       \
                    xa_[pt], bt, acc[pt][nt], 0, 0, 0);                     \
        } }

    // =========================== prologue ================================
    QK_LOAD(xfa, 0)          // first x loads before staging

    {   // stage srcT (16KB) + srcF (16KB) into LDS, write-side swizzled
        const f16* sT = srcT + (size_t)b * LL * IDF;
        const f16* sF = srcF + (size_t)b * IDF * LL;
        #pragma unroll
        for (int it = 0; it < 2; ++it) {
            int e = (it * 512 + tid) * 8;
            int l = e >> 7, i = e & 127;
            f16x8 v = *reinterpret_cast<const f16x8*>(sT + l * IDF + i);
            *reinterpret_cast<f16x8*>(
                s_srcT + l * 256 + ((i * 2) ^ ((l & 7) << 4))) = v;
        }
        #pragma unroll
        for (int it = 0; it < 2; ++it) {
            int e = (it * 512 + tid) * 8;
            int i = e >> 6, l = e & 63;
            f16x8 v = *reinterpret_cast<const f16x8*>(sF + i * LL + l);
            *reinterpret_cast<f16x8*>(
                s_srcF + i * 128 + ((l * 2) ^ ((i & 7) << 4))) = v;
        }
    }
    BAR();   // B0: staging done

    // ============================= QK^T ==================================
    #pragma unroll
    for (int pt = 0; pt < 2; ++pt)
        #pragma unroll
        for (int nt = 0; nt < 4; ++nt) acc[pt][nt] = (f32x4){0.f, 0.f, 0.f, 0.f};

    QK_LOAD(xfb, 1)
    QK_STEP(xfa, 0)
    QK_LOAD(xfa, 2)
    QK_STEP(xfb, 1)
    QK_LOAD(xfb, 3)
    QK_STEP(xfa, 2)
    QK_STEP(xfb, 3)

    // ======================= masked softmax over l =======================
    #pragma unroll
    for (int r = 0; r < 4; ++r) {
        const unsigned m0 = (mlo[r] >> c) & 1u;
        const unsigned m1 = (mlo[r] >> (16 + c)) & 1u;
        const unsigned m2 = (mhi[r] >> c) & 1u;
        const unsigned m3 = (mhi[r] >> (16 + c)) & 1u;
        #pragma unroll
        for (int pt = 0; pt < 2; ++pt) {
            if (m0) acc[pt][0][r] = -INFINITY;
            if (m1) acc[pt][1][r] = -INFINITY;
            if (m2) acc[pt][2][r] = -INFINITY;
            if (m3) acc[pt][3][r] = -INFINITY;
        }
    }
    #pragma unroll
    for (int pt = 0; pt < 2; ++pt) {
        #pragma unroll
        for (int r = 0; r < 4; ++r) {
            float mx = fmaxf(fmaxf(acc[pt][0][r], acc[pt][1][r]),
                             fmaxf(acc[pt][2][r], acc[pt][3][r]));
            mx = fmaxf(mx, __shfl_xor(mx, 1, 64));
            mx = fmaxf(mx, __shfl_xor(mx, 2, 64));
            mx = fmaxf(mx, __shfl_xor(mx, 4, 64));
            mx = fmaxf(mx, __shfl_xor(mx, 8, 64));
            float sum = 0.f;
            #pragma unroll
            for (int nt = 0; nt < 4; ++nt) {
                float e = exp2f((acc[pt][nt][r] - mx) * 1.44269504f);
                acc[pt][nt][r] = e;
                sum += e;
            }
            sum += __shfl_xor(sum, 1, 64);
            sum += __shfl_xor(sum, 2, 64);
            sum += __shfl_xor(sum, 4, 64);
            sum += __shfl_xor(sum, 8, 64);
            const float inv = 1.f / sum;
            #pragma unroll
            for (int nt = 0; nt < 4; ++nt) acc[pt][nt][r] *= inv;
        }
    }

    // ---- prob -> PV A-frags via per-wave LDS tile [32px][68] f16.
    //      Same-wave DS ordering covers the RAW (proven r4-r12).
    #pragma unroll
    for (int pt = 0; pt < 2; ++pt)
        #pragma unroll
        for (int nt = 0; nt < 4; ++nt)
            #pragma unroll
            for (int r = 0; r < 4; ++r)
                s_pw[(pt * 16 + 4 * g + r) * 68 + nt * 16 + c] =
                    (f16)acc[pt][nt][r];

    #pragma unroll
    for (int pt = 0; pt < 2; ++pt)
        #pragma unroll
        for (int ks = 0; ks < 2; ++ks) {
            const f16* pp = s_pw + (pt * 16 + c) * 68 + ks * 32 + 8 * g;
            f16x4 lo = *reinterpret_cast<const f16x4*>(pp);
            f16x4 hi = *reinterpret_cast<const f16x4*>(pp + 4);
            f16x8 v;
            #pragma unroll
            for (int j = 0; j < 4; ++j) { v[j] = lo[j]; v[4 + j] = hi[j]; }
            pa[pt][ks] = v;
        }
    BAR();   // prob exchange done; s_u becomes the xp chunk buffer

    float* abase = attn_out + (size_t)b * LL * PP + pwb;
    float* wbase = weight + (size_t)b * IDF * PP + pwb;

#define FILL_ATTN(NT)                                                       \
    {   _Pragma("unroll")                                                   \
        for (int pt = 0; pt < 2; ++pt)                                      \
            *reinterpret_cast<f32x4*>(                                      \
                s_xp + c * XPITCH + wv * 32 + pt * 16 + 4 * g) = acc[pt][NT]; }

#define FILL_PV(CH)                                                         \
    {   f32x4 a2[2];                                                        \
        a2[0] = (f32x4){0.f, 0.f, 0.f, 0.f};                                \
        a2[1] = (f32x4){0.f, 0.f, 0.f, 0.f};                                \
        _Pragma("unroll")                                                   \
        for (int ks = 0; ks < 2; ++ks) {                                    \
            const f16x8 sf = *reinterpret_cast<const f16x8*>(               \
                s_srcF + ((CH) * 16 + c) * 128 + ((ks * 64 + 16 * g) ^ cs));\
            _Pragma("unroll")                                               \
            for (int pt = 0; pt < 2; ++pt)                                  \
                a2[pt] = __builtin_amdgcn_mfma_f32_16x16x32_f16(            \
                    pa[pt][ks], sf, a2[pt], 0, 0, 0);                       \
        }                                                                   \
        _Pragma("unroll")                                                   \
        for (int pt = 0; pt < 2; ++pt)                                      \
            *reinterpret_cast<f32x4*>(                                      \
                s_xp + c * XPITCH + wv * 32 + pt * 16 + 4 * g) = a2[pt]; }

#define STORE_CHUNK(K)                                                      \
    {   float* dst = ((K) < 4)                                              \
            ? (abase + (size_t)((K) * 16) * PP)                             \
            : (wbase + (size_t)(((K) - 4) * 16) * PP);                      \
        _Pragma("unroll")                                                   \
        for (int k2 = 0; k2 < 2; ++k2) {                                    \
            int f = tid + k2 * 512;                                         \
            int row = f >> 6, u = f & 63;                                   \
            f32x4 v = *reinterpret_cast<const f32x4*>(                      \
                s_xp + row * XPITCH + u * 4);                               \
            __builtin_nontemporal_store(v,                                  \
                reinterpret_cast<f32x4*>(dst + (size_t)row * PP + u * 4));  \
        } }

#define CHUNK(K)                                                            \
    {   if ((K) < 4) { FILL_ATTN(K) } else { FILL_PV((K) - 4) }             \
        BAR();                                                              \
        STORE_CHUNK(K)                                                      \
        BAR(); }

    // ---- 12 chunks (4 attn + 8 PV), single-buffered; 16 waves/CU TLP
    //      hides the FILL/STORE serialization.
    CHUNK(0)  CHUNK(1)  CHUNK(2)  CHUNK(3)
    CHUNK(4)  CHUNK(5)  CHUNK(6)  CHUNK(7)
    CHUNK(8)  CHUNK(9)  CHUNK(10)
    { FILL_PV(7) BAR(); STORE_CHUNK(11) }   // last: no trailing barrier
    // kernel end: implicit full waitcnt drains stores
}

// ---------------------------------------------------------------------------
extern "C" void kernel_launch(void* const* d_in, const int* in_sizes, int n_in,
                              void* d_out, int out_size, void* d_ws, size_t ws_size,
                              hipStream_t stream) {
    const float*         x        = (const float*)d_in[0];
    const float*         ctx      = (const float*)d_in[1];
    const float*         Wm       = (const float*)d_in[2];
    const unsigned char* mask_raw = (const unsigned char*)d_in[3];

    float* weight   = (float*)d_out;                     // [B, IDF, H, W]
    float* attn_out = weight + (size_t)NB * IDF * PP;    // [B, L, H, W]

    // workspace: mbits u64[16] | srcF fp16 (256KB) | srcT fp16 (256KB)
    unsigned long long* mbits = (unsigned long long*)d_ws;
    f16* srcF = (f16*)((char*)d_ws + 4096);
    f16* srcT = srcF + (size_t)NB * IDF * LL;

    src_pack_kernel<<<(NB * IDF * LL) / 256, 256, 0, stream>>>(
        Wm, ctx, srcF, srcT, mask_raw, mbits);

    dim3 grid(PP / PXB, NB);
    attn_mfma_kernel<<<grid, 512, 0, stream>>>(x, srcT, srcF, mbits, weight, attn_out);
}